// Round 1
// baseline (97.259 us; speedup 1.0000x reference)
//
#include <hip/hip_runtime.h>

#define NPSI 256
#define MM 8
#define KK 4

typedef float v2f __attribute__((ext_vector_type(2)));

#if __has_builtin(__builtin_amdgcn_exp2f)
#define EXP2F(x) __builtin_amdgcn_exp2f(x)
#else
#define EXP2F(x) exp2f(x)
#endif
// hardware v_sin/v_cos take REVOLUTIONS (sin(2*pi*x)), valid |x|<=256
#define SIN_REV(x) __builtin_amdgcn_sinf(x)
#define COS_REV(x) __builtin_amdgcn_cosf(x)

#define VFMA(a,b,c) __builtin_elementwise_fma((v2f)(a),(v2f)(b),(v2f)(c))

__device__ inline float cubic_q(const float* __restrict__ q_vals, float psi) {
    float u = psi * (float)(NPSI - 1);
    int   i = (int)floorf(u);
    i = min(max(i, 0), NPSI - 2);
    float s  = u - (float)i;
    float f0 = q_vals[i];
    float f1 = q_vals[i + 1];
    float d0 = (i == 0)        ? (f1 - f0) : 0.5f * (f1 - q_vals[i - 1]);
    float d1 = (i == NPSI - 2) ? (f1 - f0) : 0.5f * (q_vals[i + 2] - f0);
    float s2 = s * s, s3 = s2 * s;
    return (2.f * s3 - 3.f * s2 + 1.f) * f0
         + (s3 - 2.f * s2 + s)         * d0
         + (-2.f * s3 + 3.f * s2)      * f1
         + (s3 - s2)                   * d1;
}

// One element per thread; v2f lanes hold the (m, m+1) mode pair.
// Same packed-ALU work per element as the 2-elem/thread version, but 2x the
// wave supply (7813 waves = 7.6/SIMD). __launch_bounds__(256,8) caps VGPRs
// at 64 so 8 waves/SIMD can actually be resident.
__global__ __launch_bounds__(256, 8) void eik_kernel(
    const float* __restrict__ t_ptr,
    const float* __restrict__ psi_a,
    const float* __restrict__ theta_a,
    const float* __restrict__ varphi_a,
    const float* __restrict__ q_vals,
    const float* __restrict__ theta0_a,
    const float* __restrict__ omega_a,
    const float* __restrict__ psi0_a,
    const float* __restrict__ psi_scale_a,
    const float* __restrict__ alpha_scale_a,
    const float* __restrict__ gh_a,        // [M,4,6]
    const int*   __restrict__ n_a,
    float* __restrict__ out,               // [2*N]: phi then apar
    int N)
{
    const int gid = blockIdx.x * blockDim.x + threadIdx.x;
    if (gid >= N) return;

    const float INV2PI = 0.15915494309189533577f;
    const float TWO_PI = 6.28318530717958647692f;
    const float NEXPC  = -0.72134752044448170368f; // -0.5*log2(e)

    const float t     = t_ptr[0];
    const float psi   = psi_a[gid];
    const float theta = theta_a[gid];
    const float vp    = varphi_a[gid] * INV2PI;   // varphi in revolutions

    // cubic Hermite interp of q (alpha0 = q*theta0 + aoff analytically; aoff cancels in y)
    const float q    = cubic_q(q_vals, psi);
    const float q2pi = q * TWO_PI;
    const float tt   = t * INV2PI;                // t in revolutions

    v2f phi = (v2f)0.f, apar = (v2f)0.f;

    #pragma unroll 1
    for (int mp = 0; mp < MM / 2; ++mp) {
        const int m = 2 * mp;
        // wave-uniform constant loads, packed as (m, m+1) pairs
        const v2f theta0 = *(const v2f*)(theta0_a + m);
        const v2f omega  = *(const v2f*)(omega_a + m);
        const v2f psi0   = *(const v2f*)(psi0_a + m);
        const v2f psc    = *(const v2f*)(psi_scale_a + m);
        const v2f asc    = *(const v2f*)(alpha_scale_a + m);
        v2f inv_ps, inv_as, nf;
        inv_ps.x = __builtin_amdgcn_rcpf(psc.x);
        inv_ps.y = __builtin_amdgcn_rcpf(psc.y);
        inv_as.x = __builtin_amdgcn_rcpf(asc.x);
        inv_as.y = __builtin_amdgcn_rcpf(asc.y);
        nf.x = (float)n_a[m];
        nf.y = (float)n_a[m + 1];
        const float* cA = gh_a + m * 24;
        const float* cB = gh_a + (m + 1) * 24;

        const v2f x  = ((v2f)psi - psi0) * inv_ps;
        const v2f x2 = x * x;
        const v2f x4 = 4.f * x2;

        // folded GH poly: p = (c0-2c3-2c5) + c1 x + c3(4x^2) + (c2+c4 x) y + c5(4y^2)
        v2f pa[4], pb[4], pf[4];
        #pragma unroll
        for (int comp = 0; comp < 4; ++comp) {
            const v2f c0 = { cA[comp*6+0], cB[comp*6+0] };
            const v2f c1 = { cA[comp*6+1], cB[comp*6+1] };
            const v2f c2 = { cA[comp*6+2], cB[comp*6+2] };
            const v2f c3 = { cA[comp*6+3], cB[comp*6+3] };
            const v2f c4 = { cA[comp*6+4], cB[comp*6+4] };
            const v2f c5 = { cA[comp*6+5], cB[comp*6+5] };
            const v2f a0 = VFMA((v2f)(-2.f), c3 + c5, c0);
            pa[comp] = VFMA(c3, x4, VFMA(c1, x, a0));
            pb[comp] = VFMA(c4, x, c2);
            pf[comp] = c5;
        }

        const v2f dth  = (v2f)theta - theta0;
        const v2f qdth = q * dth;
        v2f y          = qdth * inv_as;           // y at k=0
        const v2f dy   = q2pi * inv_as;
        const v2f dphr = nf * q;                  // phase step / 2pi
        const v2f p0r  = VFMA(nf, qdth * INV2PI,
                              VFMA(omega, (v2f)tt, -nf * vp));

        // seed trig (revolutions) + rotation recurrence over k
        v2f cp, sp, cd, sd;
        cp.x = COS_REV(p0r.x);  cp.y = COS_REV(p0r.y);
        sp.x = SIN_REV(p0r.x);  sp.y = SIN_REV(p0r.y);
        cd.x = COS_REV(dphr.x); cd.y = COS_REV(dphr.y);
        sd.x = SIN_REV(dphr.x); sd.y = SIN_REV(dphr.y);

        #pragma unroll
        for (int k = 0; k < KK; ++k) {
            const v2f t2 = VFMA(y, y, x2);            // x^2+y^2
            const v2f y4 = VFMA((v2f)4.f, t2, -x4);   // 4y^2
            const v2f ta = t2 * NEXPC;
            v2f g;
            g.x = EXP2F(ta.x);
            g.y = EXP2F(ta.y);
            const v2f gc = g * cp;
            const v2f gs = g * sp;
            const v2f p0 = VFMA(pf[0], y4, VFMA(pb[0], y, pa[0]));
            const v2f p1 = VFMA(pf[1], y4, VFMA(pb[1], y, pa[1]));
            const v2f p2 = VFMA(pf[2], y4, VFMA(pb[2], y, pa[2]));
            const v2f p3 = VFMA(pf[3], y4, VFMA(pb[3], y, pa[3]));
            phi  = VFMA(p0, gc, phi);
            phi  = VFMA(-p1, gs, phi);
            apar = VFMA(p2, gc, apar);
            apar = VFMA(-p3, gs, apar);
            if (k < KK - 1) {
                const v2f ncp = VFMA(cp, cd, -(sp * sd));
                const v2f nsp = VFMA(sp, cd,  cp * sd);
                cp = ncp; sp = nsp;
                y = y + dy;
            }
        }
    }

    // horizontal reduce over the (even-m, odd-m) lane split
    out[gid]     = phi.x + phi.y;
    out[N + gid] = apar.x + apar.y;
}

extern "C" void kernel_launch(void* const* d_in, const int* in_sizes, int n_in,
                              void* d_out, int out_size, void* d_ws, size_t ws_size,
                              hipStream_t stream) {
    // 0:t 1:psi 2:theta 3:varphi 4:q_vals 5:aoff_vals 6:theta0 7:omega
    // 8:psi0 9:psi_scale 10:alpha_scale 11:gh_coefs 12:n
    const float* t       = (const float*)d_in[0];
    const float* psi     = (const float*)d_in[1];
    const float* theta   = (const float*)d_in[2];
    const float* varphi  = (const float*)d_in[3];
    const float* q_vals  = (const float*)d_in[4];
    const float* theta0  = (const float*)d_in[6];
    const float* omega   = (const float*)d_in[7];
    const float* psi0    = (const float*)d_in[8];
    const float* psc     = (const float*)d_in[9];
    const float* asc     = (const float*)d_in[10];
    const float* gh      = (const float*)d_in[11];
    const int*   n_arr   = (const int*)d_in[12];

    const int N = in_sizes[1];
    float* out = (float*)d_out;

    const int block = 256;
    const int grid  = (N + block - 1) / block;
    eik_kernel<<<grid, block, 0, stream>>>(t, psi, theta, varphi, q_vals,
                                           theta0, omega, psi0, psc, asc,
                                           gh, n_arr, out, N);
}

// Round 2
// 91.642 us; speedup vs baseline: 1.0613x; 1.0613x over previous
//
#include <hip/hip_runtime.h>

#define NPSI 256
#define MM 8
#define KK 4
#define NMP (MM / 2)
#define TBF (NMP * 60)   // table floats: 4 mp-blocks x 30 v2f pairs

typedef float v2f __attribute__((ext_vector_type(2)));

#if __has_builtin(__builtin_amdgcn_exp2f)
#define EXP2F(x) __builtin_amdgcn_exp2f(x)
#else
#define EXP2F(x) exp2f(x)
#endif
// hardware v_sin/v_cos take REVOLUTIONS (sin(2*pi*x)), valid |x|<=256
#define SIN_REV(x) __builtin_amdgcn_sinf(x)
#define COS_REV(x) __builtin_amdgcn_cosf(x)

#define VFMA(a,b,c) __builtin_elementwise_fma((v2f)(a),(v2f)(b),(v2f)(c))

__device__ inline float cubic_q(const float* __restrict__ q_vals, float psi) {
    float u = psi * (float)(NPSI - 1);
    int   i = (int)floorf(u);
    i = min(max(i, 0), NPSI - 2);
    float s  = u - (float)i;
    float f0 = q_vals[i];
    float f1 = q_vals[i + 1];
    float d0 = (i == 0)        ? (f1 - f0) : 0.5f * (f1 - q_vals[i - 1]);
    float d1 = (i == NPSI - 2) ? (f1 - f0) : 0.5f * (q_vals[i + 2] - f0);
    float s2 = s * s, s3 = s2 * s;
    return (2.f * s3 - 3.f * s2 + 1.f) * f0
         + (s3 - 2.f * s2 + s)         * d0
         + (-2.f * s3 + 3.f * s2)      * f1
         + (s3 - s2)                   * d1;
}

// ---------------------------------------------------------------------------
// Prep: fold all per-mode constants ONCE into a compact table in d_ws.
// CDNA has no scalar FPU, so uniform float math done in the main kernel costs
// every lane VALU cycles x 500k threads. Layout: [mp][pair 0..29][lane],
// pair p of mp-block at floats mp*60 + 2p, lane = m&1 selects (m, m+1).
//   pairs 0..5 : psi0*inv_ps, inv_ps, inv_as, nf, theta0, omega
//   pairs 6+6c : a0(=c0-2c3-2c5), c1, c3, c2, c4, c5   for comp c=0..3
// ---------------------------------------------------------------------------
__global__ __launch_bounds__(64) void prep_kernel(
    const float* __restrict__ theta0_a,
    const float* __restrict__ omega_a,
    const float* __restrict__ psi0_a,
    const float* __restrict__ psi_scale_a,
    const float* __restrict__ alpha_scale_a,
    const float* __restrict__ gh_a,        // [M,4,6]
    const int*   __restrict__ n_a,
    float* __restrict__ tb)
{
    const int tid = threadIdx.x;
    if (tid < MM) {
        const int m = tid, mp = m >> 1, lane = m & 1;
        float* b = tb + mp * 60 + lane;
        const float invps = 1.0f / psi_scale_a[m];
        b[0]  = psi0_a[m] * invps;
        b[2]  = invps;
        b[4]  = 1.0f / alpha_scale_a[m];
        b[6]  = (float)n_a[m];
        b[8]  = theta0_a[m];
        b[10] = omega_a[m];
    }
    if (tid < MM * 4) {
        const int m = tid >> 2, comp = tid & 3;
        const int mp = m >> 1, lane = m & 1;
        const float* c = gh_a + m * 24 + comp * 6;
        float* b = tb + mp * 60 + (6 + comp * 6) * 2 + lane;
        b[0]  = fmaf(-2.f, c[3] + c[5], c[0]);  // a0 fold
        b[2]  = c[1];
        b[4]  = c[3];
        b[6]  = c[2];
        b[8]  = c[4];
        b[10] = c[5];
    }
}

// One element per thread; v2f lanes hold the (m, m+1) mode pair.
// (256,4): <=128 VGPRs, 4 waves/SIMD resident — no spill risk at ~75 live.
__global__ __launch_bounds__(256, 4) void eik_kernel(
    const float* __restrict__ t_ptr,
    const float* __restrict__ psi_a,
    const float* __restrict__ theta_a,
    const float* __restrict__ varphi_a,
    const float* __restrict__ q_vals,
    const float* __restrict__ tb,          // folded per-mode table (d_ws)
    float* __restrict__ out,               // [2*N]: phi then apar
    int N)
{
    const int gid = blockIdx.x * blockDim.x + threadIdx.x;
    if (gid >= N) return;

    const float INV2PI = 0.15915494309189533577f;
    const float TWO_PI = 6.28318530717958647692f;
    const float NEXPC  = -0.72134752044448170368f; // -0.5*log2(e)

    const float t     = t_ptr[0];
    const float psi   = psi_a[gid];
    const float theta = theta_a[gid];
    const float vp    = varphi_a[gid] * INV2PI;   // varphi in revolutions

    // cubic Hermite interp of q (alpha0 = q*theta0 + aoff analytically; aoff cancels in y)
    const float q    = cubic_q(q_vals, psi);
    const float q2pi = q * TWO_PI;
    const float tt   = t * INV2PI;                // t in revolutions

    v2f phi = (v2f)0.f, apar = (v2f)0.f;

    #pragma unroll 1
    for (int mp = 0; mp < NMP; ++mp) {
        // contiguous uniform table block -> scalar loads into SGPRs
        const v2f* T = (const v2f*)tb + mp * 30;
        const v2f psi0ps = T[0], invps = T[1], invas = T[2];
        const v2f nf = T[3], th0 = T[4], om = T[5];

        const v2f x  = VFMA((v2f)psi, invps, -psi0ps);
        const v2f x2 = x * x;
        const v2f x4 = 4.f * x2;

        // folded GH poly: p = a0 + c1 x + c3(4x^2) + (c2+c4 x) y + c5(4y^2)
        v2f pa[4], pb[4], pf[4];
        #pragma unroll
        for (int comp = 0; comp < 4; ++comp) {
            const v2f* B = T + 6 + comp * 6;
            pa[comp] = VFMA(B[2], x4, VFMA(B[1], x, B[0]));
            pb[comp] = VFMA(B[4], x, B[3]);
            pf[comp] = B[5];
        }

        const v2f dth  = (v2f)theta - th0;
        const v2f qdth = q * dth;
        const v2f y0   = qdth * invas;            // y at k=0
        const v2f dy   = q2pi * invas;
        const v2f dphr = nf * q;                  // phase step / 2pi
        const v2f p0r  = VFMA(nf, qdth * INV2PI,
                              VFMA(om, (v2f)tt, -nf * vp));

        // seed trig (revolutions) + rotation recurrence over k
        v2f cp, sp, cd, sd;
        cp.x = COS_REV(p0r.x);  cp.y = COS_REV(p0r.y);
        sp.x = SIN_REV(p0r.x);  sp.y = SIN_REV(p0r.y);
        cd.x = COS_REV(dphr.x); cd.y = COS_REV(dphr.y);
        sd.x = SIN_REV(dphr.x); sd.y = SIN_REV(dphr.y);

        // pass 1: batch the 8 independent exps so the trans pipe pipelines
        // instead of sitting serially inside each k's consume chain
        v2f t2v[KK], gv[KK];
        {
            v2f yk = y0;
            #pragma unroll
            for (int k = 0; k < KK; ++k) {
                const v2f t2 = VFMA(yk, yk, x2);  // x^2+y^2
                t2v[k] = t2;
                const v2f ta = t2 * NEXPC;
                gv[k].x = EXP2F(ta.x);
                gv[k].y = EXP2F(ta.y);
                yk = yk + dy;
            }
        }

        // pass 2: polynomials + rotation + accumulate
        v2f y = y0;
        #pragma unroll
        for (int k = 0; k < KK; ++k) {
            const v2f y4 = VFMA((v2f)4.f, t2v[k], -x4);   // 4y^2
            const v2f gc = gv[k] * cp;
            const v2f gs = gv[k] * sp;
            const v2f p0 = VFMA(pf[0], y4, VFMA(pb[0], y, pa[0]));
            const v2f p1 = VFMA(pf[1], y4, VFMA(pb[1], y, pa[1]));
            const v2f p2 = VFMA(pf[2], y4, VFMA(pb[2], y, pa[2]));
            const v2f p3 = VFMA(pf[3], y4, VFMA(pb[3], y, pa[3]));
            phi  = VFMA(p0, gc, phi);
            phi  = VFMA(-p1, gs, phi);
            apar = VFMA(p2, gc, apar);
            apar = VFMA(-p3, gs, apar);
            if (k < KK - 1) {
                const v2f ncp = VFMA(cp, cd, -(sp * sd));
                const v2f nsp = VFMA(sp, cd,  cp * sd);
                cp = ncp; sp = nsp;
                y = y + dy;
            }
        }
    }

    // horizontal reduce over the (even-m, odd-m) lane split
    out[gid]     = phi.x + phi.y;
    out[N + gid] = apar.x + apar.y;
}

extern "C" void kernel_launch(void* const* d_in, const int* in_sizes, int n_in,
                              void* d_out, int out_size, void* d_ws, size_t ws_size,
                              hipStream_t stream) {
    // 0:t 1:psi 2:theta 3:varphi 4:q_vals 5:aoff_vals 6:theta0 7:omega
    // 8:psi0 9:psi_scale 10:alpha_scale 11:gh_coefs 12:n
    const float* t       = (const float*)d_in[0];
    const float* psi     = (const float*)d_in[1];
    const float* theta   = (const float*)d_in[2];
    const float* varphi  = (const float*)d_in[3];
    const float* q_vals  = (const float*)d_in[4];
    const float* theta0  = (const float*)d_in[6];
    const float* omega   = (const float*)d_in[7];
    const float* psi0    = (const float*)d_in[8];
    const float* psc     = (const float*)d_in[9];
    const float* asc     = (const float*)d_in[10];
    const float* gh      = (const float*)d_in[11];
    const int*   n_arr   = (const int*)d_in[12];

    const int N = in_sizes[1];
    float* out = (float*)d_out;
    float* tb  = (float*)d_ws;   // workspace (poison-filled by harness, fully
                                 // rewritten by prep_kernel every launch)

    prep_kernel<<<1, 64, 0, stream>>>(theta0, omega, psi0, psc, asc,
                                      gh, n_arr, tb);

    const int block = 256;
    const int grid  = (N + block - 1) / block;
    eik_kernel<<<grid, block, 0, stream>>>(t, psi, theta, varphi, q_vals,
                                           tb, out, N);
}